// Round 3
// baseline (357.107 us; speedup 1.0000x reference)
//
#include <hip/hip_runtime.h>
#include <math.h>

// ChannelDropout: out[b,c,t] = sig[b,c,t] * kept[b,c] / (1e-8 + proba[b,c])
//   kept[b,c]  = ||pos[b,c] - center|| > 0.2
//   proba[b,c] = mean_i( ||pos[b,c] - mc[i]|| > 0.2 ), i in [0,100)
//
// Single fused kernel. One block per 4 contiguous rows:
//  - wave w (of 4) computes row r0+w's scale: 64 lanes split the 100 MC
//    centers, shuffle-reduce, lane 0 adds the kept test and stores to LDS.
//  - one __syncthreads, then all 256 threads stream the 4 rows' 3000 float4
//    (12000 floats) with plain coalesced float4 load/store — the same access
//    pattern as the harness fills that measure 6.5 TB/s on this chip.
// Traffic: 210 MB read + 210 MB write (mandatory) + ~3.4 MB mc re-reads
// (L2-absorbed). HBM roofline ~67 us for the dispatch.

typedef float vfloat4 __attribute__((ext_vector_type(4)));

#define ROWS_PER_BLOCK 4

__global__ __launch_bounds__(256) void channel_dropout_fused(
    const float* __restrict__ sig,
    const float* __restrict__ pos,      // (rows, 2)
    const float* __restrict__ center,   // (2,)
    const float* __restrict__ mc,       // (NMC, 2)
    float* __restrict__ out,
    int n4_per_row,                     // T/4 (=750)
    int T, int rows, int NMC)
{
    __shared__ float s_scale[ROWS_PER_BLOCK];

    const int r0   = blockIdx.x * ROWS_PER_BLOCK;
    const int wave = threadIdx.x >> 6;        // 0..3
    const int lane = threadIdx.x & 63;
    const int nr   = min(ROWS_PER_BLOCK, rows - r0);

    const int row = r0 + wave;
    if (wave < nr) {
        const float px = pos[2 * row + 0];
        const float py = pos[2 * row + 1];
        float cnt = 0.0f;
        for (int j = lane; j < NMC; j += 64) {
            const float dx = px - mc[2 * j + 0];
            const float dy = py - mc[2 * j + 1];
            cnt += (sqrtf(dx * dx + dy * dy) > 0.2f) ? 1.0f : 0.0f;
        }
        #pragma unroll
        for (int off = 32; off > 0; off >>= 1)
            cnt += __shfl_down(cnt, off, 64);
        if (lane == 0) {
            const float dx = px - center[0];
            const float dy = py - center[1];
            const float kept =
                (sqrtf(dx * dx + dy * dy) > 0.2f) ? 1.0f : 0.0f;
            const float proba = cnt / (float)NMC;
            s_scale[wave] = kept / (1e-8f + proba);
        }
    }
    __syncthreads();

    const float sc0 = s_scale[0];
    const float sc1 = s_scale[1];
    const float sc2 = s_scale[2];
    const float sc3 = s_scale[3];

    const size_t base4 = (size_t)r0 * (size_t)n4_per_row;
    const int total4 = nr * n4_per_row;
    const int n1 = n4_per_row, n2 = 2 * n4_per_row, n3 = 3 * n4_per_row;

    const vfloat4* __restrict__ in4  = (const vfloat4*)sig + base4;
    vfloat4* __restrict__       out4 = (vfloat4*)out + base4;

    for (int i = threadIdx.x; i < total4; i += 256) {
        const float sc = (i < n1) ? sc0 : (i < n2) ? sc1 : (i < n3) ? sc2
                                                                    : sc3;
        vfloat4 v = in4[i];
        v *= sc;
        out4[i] = v;
    }

    // scalar tail for T % 4 != 0 (not hit for T=3000)
    const int tail_start = n4_per_row << 2;
    if (tail_start < T) {
        for (int k = threadIdx.x; k < nr * (T - tail_start); k += 256) {
            const int r  = k / (T - tail_start);
            const int tt = tail_start + (k - r * (T - tail_start));
            const float sc = (r == 0) ? sc0 : (r == 1) ? sc1 : (r == 2) ? sc2
                                                                        : sc3;
            const size_t off = (size_t)(r0 + r) * (size_t)T + tt;
            out[off] = sig[off] * sc;
        }
    }
}

extern "C" void kernel_launch(void* const* d_in, const int* in_sizes, int n_in,
                              void* d_out, int out_size, void* d_ws, size_t ws_size,
                              hipStream_t stream) {
    const float* sig    = (const float*)d_in[0];  // (B, C, T) f32
    const float* pos    = (const float*)d_in[1];  // (B, C, 2) f32
    const float* center = (const float*)d_in[2];  // (2,)      f32
    const float* mc     = (const float*)d_in[3];  // (N, 2)    f32
    float* out          = (float*)d_out;          // (B, C, T) f32

    const int rows = in_sizes[1] / 2;             // B*C = 17472
    const int T    = in_sizes[0] / rows;          // 3000
    const int NMC  = in_sizes[3] / 2;             // 100
    const int n4   = T / 4;                       // 750

    const int blocks = (rows + ROWS_PER_BLOCK - 1) / ROWS_PER_BLOCK;
    channel_dropout_fused<<<blocks, 256, 0, stream>>>(
        sig, pos, center, mc, out, n4, T, rows, NMC);
}